// Round 1
// baseline (517.905 us; speedup 1.0000x reference)
//
#include <hip/hip_runtime.h>
#include <math.h>

constexpr int IN_DIM  = 256;
constexpr int HID     = 128;
constexpr int OUT_DIM = 64;

constexpr int BROWS   = 128;                 // rows per bucket
constexpr int NBUCK   = 782;                 // ceil(100000/128)
constexpr int CAP     = 4608;                // mean 4096 + 8 sigma
constexpr int CHUNK   = 8192;                // edges per bin block
constexpr int GC_STRIDE = 16;                // 64B line per cursor (atomic de-contention)

typedef short  bf16x8 __attribute__((ext_vector_type(8)));
typedef float  f32x4  __attribute__((ext_vector_type(4)));

__device__ __forceinline__ unsigned short f2bf(float x) {
    union { float f; unsigned u; } v; v.f = x;
    unsigned r = v.u + 0x7FFF + ((v.u >> 16) & 1);   // RNE
    return (unsigned short)(r >> 16);
}

// ---------------------------------------------------------------------------
// W1T: bf16 transpose of W1 -> W1T[n][k], n<128, k<256.
// ---------------------------------------------------------------------------
__global__ __launch_bounds__(256) void w1t_kernel(const float* __restrict__ W1,
                                                  unsigned short* __restrict__ W1T)
{
    int idx = blockIdx.x * 256 + threadIdx.x;     // = k*128 + n
    int k = idx >> 7;
    int n = idx & 127;
    W1T[n * IN_DIM + k] = f2bf(W1[idx]);
}

// W2T: bf16 transpose of W2 -> W2T[n][k], n<64, k<128.
__global__ __launch_bounds__(256) void w2t_kernel(const float* __restrict__ W2,
                                                  unsigned short* __restrict__ W2T)
{
    int idx = blockIdx.x * 256 + threadIdx.x;     // = k*64 + n, 8192 total
    int k = idx >> 6;
    int n = idx & 63;
    W2T[n * HID + k] = f2bf(W2[idx]);
}

// ---------------------------------------------------------------------------
// fc1 via bf16 MFMA 16x16x32. Full K=256 staged once (33 KB LDS, 1 barrier).
// ---------------------------------------------------------------------------
constexpr int PADK = 264;   // 256 + 8 bf16 pad

__global__ __launch_bounds__(256) void fc1_mfma(const float* __restrict__ feat,
                                                const unsigned short* __restrict__ W1T,
                                                const float* __restrict__ b1,
                                                unsigned short* __restrict__ h1b, int N)
{
    __shared__ unsigned short sA[64 * PADK];
    const int t    = threadIdx.x;
    const int lane = t & 63;
    const int w    = t >> 6;
    const int quad = lane >> 4;
    const int ln15 = lane & 15;
    const int row0 = blockIdx.x * 64;

#pragma unroll
    for (int i = 0; i < 16; ++i) {
        int flat = i * 256 + t;          // 0..4095
        int r    = flat >> 6;
        int k4   = flat & 63;
        int gr   = row0 + r;
        float4 v = make_float4(0.f, 0.f, 0.f, 0.f);
        if (gr < N)
            v = *(const float4*)&feat[(size_t)gr * IN_DIM + k4 * 4];
        ushort4 o;
        o.x = f2bf(v.x); o.y = f2bf(v.y); o.z = f2bf(v.z); o.w = f2bf(v.w);
        *(ushort4*)&sA[r * PADK + k4 * 4] = o;
    }
    __syncthreads();

    f32x4 acc[8];
#pragma unroll
    for (int i = 0; i < 8; ++i) acc[i] = (f32x4){0.f, 0.f, 0.f, 0.f};

#pragma unroll
    for (int ks = 0; ks < 8; ++ks) {
        bf16x8 afrag = *(const bf16x8*)&sA[(w * 16 + ln15) * PADK + ks * 32 + quad * 8];
#pragma unroll
        for (int nt = 0; nt < 8; ++nt) {
            bf16x8 bfrag = *(const bf16x8*)&W1T[(size_t)(nt * 16 + ln15) * IN_DIM + ks * 32 + quad * 8];
            acc[nt] = __builtin_amdgcn_mfma_f32_16x16x32_bf16(afrag, bfrag, acc[nt], 0, 0, 0);
        }
    }

#pragma unroll
    for (int nt = 0; nt < 8; ++nt) {
        int col = nt * 16 + ln15;
        float bias = b1[col];
#pragma unroll
        for (int r = 0; r < 4; ++r) {
            int grow = row0 + w * 16 + quad * 4 + r;
            if (grow < N)
                h1b[(size_t)grow * HID + col] = f2bf(acc[nt][r] + bias);
        }
    }
}

// ---------------------------------------------------------------------------
// bin: bucket edges by row>>7. Entry x = (col<<8) | (row&127)<<25.
// gCursor padded to one counter per 64B line: 306K global atomics previously
// hit 16 cache lines; now 782 lines -> per-line serialization ~49x lower.
// ---------------------------------------------------------------------------
__global__ __launch_bounds__(256) void bin_kernel(const int* __restrict__ erow,
                                                  const int* __restrict__ ecol,
                                                  const float* __restrict__ eval,
                                                  int* __restrict__ gCursor,
                                                  int2* __restrict__ binned, int E)
{
    __shared__ int sCnt[NBUCK];
    __shared__ int sBase[NBUCK];
    const int t = threadIdx.x;
    const int e0 = blockIdx.x * CHUNK;
    const int eEnd = min(e0 + CHUNK, E);

    for (int i = t; i < NBUCK; i += 256) sCnt[i] = 0;
    __syncthreads();

    for (int e = e0 + t; e < eEnd; e += 256)
        atomicAdd(&sCnt[erow[e] >> 7], 1);
    __syncthreads();

    for (int i = t; i < NBUCK; i += 256) {
        int c = sCnt[i];
        sBase[i] = c ? atomicAdd(&gCursor[i * GC_STRIDE], c) : 0;
        sCnt[i] = 0;
    }
    __syncthreads();

    for (int e = e0 + t; e < eEnd; e += 256) {
        int   r = erow[e];
        int   c = ecol[e];
        float v = eval[e];
        int   b = r >> 7;
        int off = sBase[b] + atomicAdd(&sCnt[b], 1);
        if (off < CAP)
            binned[(size_t)b * CAP + off] = make_int2((c << 8) | ((r & 127) << 25),
                                                      __float_as_int(v));
    }
}

// ---------------------------------------------------------------------------
// sort_spmm: FUSED per-bucket row-sort (into LDS, no edges2 round-trip) +
// gather-accumulate + relu + bf16 h2 store.
// One 512-thread block per bucket. Phases:
//   1. LDS histogram of local rows (coalesced binned read)
//   2. exclusive scan (128 rows)
//   3. scatter edges into LDS sE[] grouped by row (re-read is L2-hot)
//   4. each of 8 waves streams rows [w*16, w*16+16): contiguous LDS edge
//      range, fixed 16-deep gather batches (2x prior MLP), scalar row-change
//      flush. No per-row pipeline drain.
// LDS: 36 KB edges + ~1.5 KB tables -> 3 blocks/CU, 24 waves/CU.
// ---------------------------------------------------------------------------
__global__ __launch_bounds__(512, 6) void sort_spmm(const int* __restrict__ gCursor,
                                                    const int2* __restrict__ binned,
                                                    const unsigned short* __restrict__ h1b,
                                                    unsigned* __restrict__ h2b, int N)
{
    __shared__ int2 sE[CAP + 16];           // +16: zero pad for fixed batches
    __shared__ int sHist[BROWS];
    __shared__ int sStart[BROWS + 1];
    __shared__ int sCur[BROWS];
    const int t  = threadIdx.x;
    const int b  = blockIdx.x;
    const int nE = min(gCursor[b * GC_STRIDE], CAP);
    const size_t base = (size_t)b * CAP;

    if (t < BROWS) sHist[t] = 0;
    __syncthreads();

    for (int i = t; i < nE; i += 512)
        atomicAdd(&sHist[(unsigned)binned[base + i].x >> 25], 1);
    __syncthreads();

    if (t < BROWS) sStart[t + 1] = sHist[t];
    if (t == 0) sStart[0] = 0;
    __syncthreads();
    for (int o = 1; o < BROWS; o <<= 1) {
        int v = 0;
        if (t < BROWS) {
            v = sStart[t + 1];
            if (t >= o) v += sStart[t + 1 - o];
        }
        __syncthreads();
        if (t < BROWS) sStart[t + 1] = v;
        __syncthreads();
    }
    if (t < BROWS) sCur[t] = sStart[t];
    if (t < 16) sE[nE + t] = make_int2(0, 0);   // pad: col 0, val 0
    __syncthreads();

    for (int i = t; i < nE; i += 512) {
        int2 p = binned[base + i];
        int rl = (unsigned)p.x >> 25;
        int pos = atomicAdd(&sCur[rl], 1);
        sE[pos] = p;
    }
    __syncthreads();

    // ---- streaming gather-accumulate: wave w owns rows [w*16, w*16+16) ----
    const int lane  = t & 63;
    const int lane4 = lane * 4;
    const int w     = t >> 6;
    const int r0    = w * 16;
    const int ws    = __builtin_amdgcn_readfirstlane(sStart[r0]);
    const int we    = __builtin_amdgcn_readfirstlane(sStart[r0 + 16]);
    const char* h1base = (const char*)h1b;
    const int gRow0 = b * BROWS;

    float ax = 0.f, ay = 0.f;
    int curRow = -1;                         // scalar (uniform) running row

    for (int j = ws; j < we; j += 16) {
        int      sx[16];
        float    vv[16];
        unsigned g[16];
#pragma unroll
        for (int u = 0; u < 16; ++u) {
            int2 e = sE[j + u];              // uniform addr -> broadcast
            sx[u] = __builtin_amdgcn_readfirstlane(e.x);
            vv[u] = __int_as_float(e.y);
        }
#pragma unroll
        for (int u = 0; u < 16; ++u)         // 16 gathers in flight
            g[u] = *(const unsigned*)(h1base + (sx[u] & 0x01FFFFFF) + lane4);
#pragma unroll
        for (int u = 0; u < 16; ++u) {
            if (j + u < we) {                // scalar bound check (tail batch)
                int nr = (int)((unsigned)sx[u] >> 25);
                if (nr != curRow) {          // scalar, rarely taken (~1/32)
                    if (curRow >= 0) {
                        int gr = gRow0 + curRow;
                        if (gr < N)
                            h2b[(size_t)gr * 64 + lane] =
                                (unsigned)f2bf(fmaxf(ax, 0.f)) |
                                ((unsigned)f2bf(fmaxf(ay, 0.f)) << 16);
                    }
                    for (int q = (curRow < 0) ? r0 : curRow + 1; q < nr; ++q) {
                        int gr = gRow0 + q;  // empty row: P ~ e^-32, kept for safety
                        if (gr < N) h2b[(size_t)gr * 64 + lane] = 0u;
                    }
                    curRow = nr; ax = 0.f; ay = 0.f;
                }
                float v = vv[u];
                ax += v * __uint_as_float(g[u] << 16);
                ay += v * __uint_as_float(g[u] & 0xFFFF0000u);
            }
        }
    }
    // flush last row + zero any trailing empty rows of this wave
    if (curRow >= 0) {
        int gr = gRow0 + curRow;
        if (gr < N)
            h2b[(size_t)gr * 64 + lane] =
                (unsigned)f2bf(fmaxf(ax, 0.f)) |
                ((unsigned)f2bf(fmaxf(ay, 0.f)) << 16);
    }
    for (int q = (curRow < 0) ? r0 : curRow + 1; q < r0 + 16; ++q) {
        int gr = gRow0 + q;
        if (gr < N) h2b[(size_t)gr * 64 + lane] = 0u;
    }
}

// ---------------------------------------------------------------------------
// fc2 via bf16 MFMA 16x16x32 + bias + log_softmax, all in registers.
// ---------------------------------------------------------------------------
__global__ __launch_bounds__(256) void fc2_mfma(const unsigned short* __restrict__ h2b,
                                                const unsigned short* __restrict__ W2T,
                                                const float* __restrict__ b2,
                                                float* __restrict__ out, int N)
{
    const int t    = threadIdx.x;
    const int lane = t & 63;
    const int w    = t >> 6;
    const int quad = lane >> 4;
    const int ln15 = lane & 15;
    const int row0 = blockIdx.x * 64;

    int arow = row0 + w * 16 + ln15;
    if (arow >= N) arow = N - 1;

    f32x4 acc[4];
#pragma unroll
    for (int i = 0; i < 4; ++i) acc[i] = (f32x4){0.f, 0.f, 0.f, 0.f};

#pragma unroll
    for (int ks = 0; ks < 4; ++ks) {
        bf16x8 afrag = *(const bf16x8*)&h2b[(size_t)arow * HID + ks * 32 + quad * 8];
#pragma unroll
        for (int nt = 0; nt < 4; ++nt) {
            bf16x8 bfrag = *(const bf16x8*)&W2T[(size_t)(nt * 16 + ln15) * HID + ks * 32 + quad * 8];
            acc[nt] = __builtin_amdgcn_mfma_f32_16x16x32_bf16(afrag, bfrag, acc[nt], 0, 0, 0);
        }
    }

    float bias[4];
#pragma unroll
    for (int nt = 0; nt < 4; ++nt) bias[nt] = b2[nt * 16 + ln15];

#pragma unroll
    for (int r = 0; r < 4; ++r) {
        float v[4];
#pragma unroll
        for (int nt = 0; nt < 4; ++nt) v[nt] = acc[nt][r] + bias[nt];

        float m = fmaxf(fmaxf(v[0], v[1]), fmaxf(v[2], v[3]));
#pragma unroll
        for (int o = 1; o < 16; o <<= 1) m = fmaxf(m, __shfl_xor(m, o));
        float s = __expf(v[0] - m) + __expf(v[1] - m) +
                  __expf(v[2] - m) + __expf(v[3] - m);
#pragma unroll
        for (int o = 1; o < 16; o <<= 1) s += __shfl_xor(s, o);
        float ls = __logf(s);

        int grow = row0 + w * 16 + quad * 4 + r;
        if (grow < N) {
#pragma unroll
            for (int nt = 0; nt < 4; ++nt)
                out[(size_t)grow * OUT_DIM + nt * 16 + ln15] = v[nt] - m - ls;
        }
    }
}

extern "C" void kernel_launch(void* const* d_in, const int* in_sizes, int n_in,
                              void* d_out, int out_size, void* d_ws, size_t ws_size,
                              hipStream_t stream) {
    const float* feat = (const float*)d_in[0];
    const int*   erow = (const int*)d_in[1];
    const int*   ecol = (const int*)d_in[2];
    const float* eval = (const float*)d_in[3];
    const float* W1   = (const float*)d_in[4];
    const float* b1   = (const float*)d_in[5];
    const float* W2   = (const float*)d_in[6];
    const float* b2   = (const float*)d_in[7];
    float*       out  = (float*)d_out;

    const int N = in_sizes[0] / IN_DIM;
    const int E = in_sizes[1];

    // ws: h1b 25.6MB | h2b 25.6MB | binned 28.8MB | W1T 64KB | W2T 16KB |
    //     gCursor 50KB (line-padded)
    unsigned short* h1b    = (unsigned short*)d_ws;
    unsigned short* h2b    = h1b + (size_t)N * HID;
    int2*           binned = (int2*)(h2b + (size_t)N * HID);
    unsigned short* W1T    = (unsigned short*)(binned + (size_t)NBUCK * CAP);
    unsigned short* W2T    = W1T + IN_DIM * HID;
    int*            gCursor= (int*)(W2T + HID * OUT_DIM);

    hipMemsetAsync(gCursor, 0, NBUCK * GC_STRIDE * sizeof(int), stream);

    w1t_kernel<<<(IN_DIM * HID) / 256, 256, 0, stream>>>(W1, W1T);
    w2t_kernel<<<(HID * OUT_DIM) / 256, 256, 0, stream>>>(W2, W2T);
    fc1_mfma<<<(N + 63) / 64, 256, 0, stream>>>(feat, W1T, b1, h1b, N);
    bin_kernel<<<(E + CHUNK - 1) / CHUNK, 256, 0, stream>>>(erow, ecol, eval,
                                                            gCursor, binned, E);
    sort_spmm<<<NBUCK, 512, 0, stream>>>(gCursor, binned, h1b,
                                         (unsigned*)h2b, N);
    fc2_mfma<<<(N + 63) / 64, 256, 0, stream>>>(h2b, W2T, b2, out, N);
}

// Round 2
// 515.344 us; speedup vs baseline: 1.0050x; 1.0050x over previous
//
#include <hip/hip_runtime.h>
#include <math.h>

constexpr int IN_DIM  = 256;
constexpr int HID     = 128;
constexpr int OUT_DIM = 64;

constexpr int BROWS   = 128;                 // rows per bucket
constexpr int NBUCK   = 782;                 // ceil(100000/128)
constexpr int CAP     = 4608;                // mean 4096 + 8 sigma (binned)
constexpr int CAP2    = 5504;                // CAP + 128*7 (row-padded edges2), mult of 8
constexpr int CHUNK   = 8192;                // edges per bin block
constexpr int GC_STRIDE = 16;                // 64B line per cursor (atomic de-contention)

typedef short  bf16x8 __attribute__((ext_vector_type(8)));
typedef float  f32x4  __attribute__((ext_vector_type(4)));
typedef int    i32x4  __attribute__((ext_vector_type(4)));

__device__ __forceinline__ unsigned short f2bf(float x) {
    union { float f; unsigned u; } v; v.f = x;
    unsigned r = v.u + 0x7FFF + ((v.u >> 16) & 1);   // RNE
    return (unsigned short)(r >> 16);
}

// ---------------------------------------------------------------------------
// W1T: bf16 transpose of W1 -> W1T[n][k], n<128, k<256.
// ---------------------------------------------------------------------------
__global__ __launch_bounds__(256) void w1t_kernel(const float* __restrict__ W1,
                                                  unsigned short* __restrict__ W1T)
{
    int idx = blockIdx.x * 256 + threadIdx.x;     // = k*128 + n
    int k = idx >> 7;
    int n = idx & 127;
    W1T[n * IN_DIM + k] = f2bf(W1[idx]);
}

// W2T: bf16 transpose of W2 -> W2T[n][k], n<64, k<128.
__global__ __launch_bounds__(256) void w2t_kernel(const float* __restrict__ W2,
                                                  unsigned short* __restrict__ W2T)
{
    int idx = blockIdx.x * 256 + threadIdx.x;     // = k*64 + n, 8192 total
    int k = idx >> 6;
    int n = idx & 63;
    W2T[n * HID + k] = f2bf(W2[idx]);
}

// ---------------------------------------------------------------------------
// fc1 via bf16 MFMA 16x16x32. Full K=256 staged once (33 KB LDS, 1 barrier).
// ---------------------------------------------------------------------------
constexpr int PADK = 264;   // 256 + 8 bf16 pad

__global__ __launch_bounds__(256) void fc1_mfma(const float* __restrict__ feat,
                                                const unsigned short* __restrict__ W1T,
                                                const float* __restrict__ b1,
                                                unsigned short* __restrict__ h1b, int N)
{
    __shared__ unsigned short sA[64 * PADK];
    const int t    = threadIdx.x;
    const int lane = t & 63;
    const int w    = t >> 6;
    const int quad = lane >> 4;
    const int ln15 = lane & 15;
    const int row0 = blockIdx.x * 64;

#pragma unroll
    for (int i = 0; i < 16; ++i) {
        int flat = i * 256 + t;          // 0..4095
        int r    = flat >> 6;
        int k4   = flat & 63;
        int gr   = row0 + r;
        float4 v = make_float4(0.f, 0.f, 0.f, 0.f);
        if (gr < N)
            v = *(const float4*)&feat[(size_t)gr * IN_DIM + k4 * 4];
        ushort4 o;
        o.x = f2bf(v.x); o.y = f2bf(v.y); o.z = f2bf(v.z); o.w = f2bf(v.w);
        *(ushort4*)&sA[r * PADK + k4 * 4] = o;
    }
    __syncthreads();

    f32x4 acc[8];
#pragma unroll
    for (int i = 0; i < 8; ++i) acc[i] = (f32x4){0.f, 0.f, 0.f, 0.f};

#pragma unroll
    for (int ks = 0; ks < 8; ++ks) {
        bf16x8 afrag = *(const bf16x8*)&sA[(w * 16 + ln15) * PADK + ks * 32 + quad * 8];
#pragma unroll
        for (int nt = 0; nt < 8; ++nt) {
            bf16x8 bfrag = *(const bf16x8*)&W1T[(size_t)(nt * 16 + ln15) * IN_DIM + ks * 32 + quad * 8];
            acc[nt] = __builtin_amdgcn_mfma_f32_16x16x32_bf16(afrag, bfrag, acc[nt], 0, 0, 0);
        }
    }

#pragma unroll
    for (int nt = 0; nt < 8; ++nt) {
        int col = nt * 16 + ln15;
        float bias = b1[col];
#pragma unroll
        for (int r = 0; r < 4; ++r) {
            int grow = row0 + w * 16 + quad * 4 + r;
            if (grow < N)
                h1b[(size_t)grow * HID + col] = f2bf(acc[nt][r] + bias);
        }
    }
}

// ---------------------------------------------------------------------------
// bin: bucket edges by row>>7. Entry x = (col<<8) | (row&127)<<25.
// gCursor padded to one counter per 64B line (306K global atomics over 782
// lines instead of 16).
// ---------------------------------------------------------------------------
__global__ __launch_bounds__(256) void bin_kernel(const int* __restrict__ erow,
                                                  const int* __restrict__ ecol,
                                                  const float* __restrict__ eval,
                                                  int* __restrict__ gCursor,
                                                  int2* __restrict__ binned, int E)
{
    __shared__ int sCnt[NBUCK];
    __shared__ int sBase[NBUCK];
    const int t = threadIdx.x;
    const int e0 = blockIdx.x * CHUNK;
    const int eEnd = min(e0 + CHUNK, E);

    for (int i = t; i < NBUCK; i += 256) sCnt[i] = 0;
    __syncthreads();

    for (int e = e0 + t; e < eEnd; e += 256)
        atomicAdd(&sCnt[erow[e] >> 7], 1);
    __syncthreads();

    for (int i = t; i < NBUCK; i += 256) {
        int c = sCnt[i];
        sBase[i] = c ? atomicAdd(&gCursor[i * GC_STRIDE], c) : 0;
        sCnt[i] = 0;
    }
    __syncthreads();

    for (int e = e0 + t; e < eEnd; e += 256) {
        int   r = erow[e];
        int   c = ecol[e];
        float v = eval[e];
        int   b = r >> 7;
        int off = sBase[b] + atomicAdd(&sCnt[b], 1);
        if (off < CAP)
            binned[(size_t)b * CAP + off] = make_int2((c << 8) | ((r & 127) << 25),
                                                      __float_as_int(v));
    }
}

// ---------------------------------------------------------------------------
// sort_bucket3: per-bucket row-grouping with per-row PADDING to a multiple
// of 8 edges (pad = col 0, val 0.0 -> gather of h1 row 0, times zero).
// This removes spmm's serial scalar tail entirely: every row is processed
// with full-width pipelined gather batches.
// Pass 1: coalesced read + LDS histogram. Scan PADDED counts. Pass 2:
// re-read (L2-hot), scatter to final slot. Pass 3: zero-fill pad slots
// (disjoint from scatter slots -> no barrier needed).
// Worst case sum of padded counts = CAP + 128*7 = 5504 = CAP2.
// ---------------------------------------------------------------------------
__global__ __launch_bounds__(256) void sort_bucket3(const int* __restrict__ gCursor,
                                                    const int2* __restrict__ binned,
                                                    int2* __restrict__ edges2,
                                                    int2* __restrict__ rowIdx, int N)
{
    __shared__ int sHist[BROWS];
    __shared__ int sStart[BROWS + 1];
    __shared__ int sCur[BROWS];
    const int t  = threadIdx.x;
    const int b  = blockIdx.x;
    const int nE = min(gCursor[b * GC_STRIDE], CAP);
    const size_t baseIn  = (size_t)b * CAP;
    const size_t baseOut = (size_t)b * CAP2;

    if (t < BROWS) sHist[t] = 0;
    __syncthreads();

    for (int i = t; i < nE; i += 256)
        atomicAdd(&sHist[(unsigned)binned[baseIn + i].x >> 25], 1);
    __syncthreads();

    if (t < BROWS) sStart[t + 1] = (sHist[t] + 7) & ~7;   // padded count
    if (t == 0) sStart[0] = 0;
    __syncthreads();
    for (int o = 1; o < BROWS; o <<= 1) {
        int v = 0;
        if (t < BROWS) {
            v = sStart[t + 1];
            if (t >= o) v += sStart[t + 1 - o];
        }
        __syncthreads();
        if (t < BROWS) sStart[t + 1] = v;
        __syncthreads();
    }
    if (t < BROWS) sCur[t] = sStart[t];
    __syncthreads();

    for (int i = t; i < nE; i += 256) {
        int2 p = binned[baseIn + i];
        int rl = (unsigned)p.x >> 25;
        int pos = atomicAdd(&sCur[rl], 1);
        edges2[baseOut + pos] = p;
    }

    // pad fill + rowIdx (pad slots [h, ph) are never touched by the scatter)
    if (t < BROWS) {
        int h  = sHist[t];
        int ph = (h + 7) & ~7;
        size_t p0 = baseOut + sStart[t];
        for (int k = h; k < ph; ++k)
            edges2[p0 + k] = make_int2(0, 0);
        int rr = b * BROWS + t;
        if (rr < N)
            rowIdx[rr] = make_int2((int)p0, (int)(p0 + ph));
    }
}

// ---------------------------------------------------------------------------
// spmm: gather-accumulate + relu, store bf16 h2. ONE wave per row.
// Row edge count is a multiple of 8 (padded by sort), so the loop body is
// only full pipelined batches: 16 gathers in flight (two int4 edge loads
// per 2 edges, nontemporal: single-use stream, keep L2/L3 for h1).
// 100K waves -> 25K blocks: elastic, perfectly balanced.
// ---------------------------------------------------------------------------
__global__ __launch_bounds__(256) void spmm_kernel(const int2* __restrict__ rowIdx,
                                                   const int2* __restrict__ edges2,
                                                   const unsigned short* __restrict__ h1b,
                                                   unsigned* __restrict__ h2b, int N)
{
    const int lane  = threadIdx.x & 63;
    const int lane4 = lane * 4;
    const int r     = (blockIdx.x * blockDim.x + threadIdx.x) >> 6;
    if (r >= N) return;
    const char* h1base = (const char*)h1b;

    const int2 se = rowIdx[r];
    int j = se.x;
    const int jend = se.y;
    float ax = 0.f, ay = 0.f;

    for (; j + 16 <= jend; j += 16) {
        i32x4 q[8];
#pragma unroll
        for (int u = 0; u < 8; ++u)
            q[u] = __builtin_nontemporal_load((const i32x4*)&edges2[j + u * 2]);
        unsigned g[16];
#pragma unroll
        for (int u = 0; u < 8; ++u) {
            g[2 * u]     = *(const unsigned*)(h1base + (q[u].x & 0x01FFFFFF) + lane4);
            g[2 * u + 1] = *(const unsigned*)(h1base + (q[u].z & 0x01FFFFFF) + lane4);
        }
#pragma unroll
        for (int u = 0; u < 8; ++u) {
            float v0 = __int_as_float(q[u].y);
            float v1 = __int_as_float(q[u].w);
            ax += v0 * __uint_as_float(g[2 * u] << 16);
            ay += v0 * __uint_as_float(g[2 * u] & 0xFFFF0000u);
            ax += v1 * __uint_as_float(g[2 * u + 1] << 16);
            ay += v1 * __uint_as_float(g[2 * u + 1] & 0xFFFF0000u);
        }
    }
    if (j < jend) {   // exactly 8 remain (counts are multiples of 8)
        i32x4 q[4];
#pragma unroll
        for (int u = 0; u < 4; ++u)
            q[u] = __builtin_nontemporal_load((const i32x4*)&edges2[j + u * 2]);
        unsigned g[8];
#pragma unroll
        for (int u = 0; u < 4; ++u) {
            g[2 * u]     = *(const unsigned*)(h1base + (q[u].x & 0x01FFFFFF) + lane4);
            g[2 * u + 1] = *(const unsigned*)(h1base + (q[u].z & 0x01FFFFFF) + lane4);
        }
#pragma unroll
        for (int u = 0; u < 4; ++u) {
            float v0 = __int_as_float(q[u].y);
            float v1 = __int_as_float(q[u].w);
            ax += v0 * __uint_as_float(g[2 * u] << 16);
            ay += v0 * __uint_as_float(g[2 * u] & 0xFFFF0000u);
            ax += v1 * __uint_as_float(g[2 * u + 1] << 16);
            ay += v1 * __uint_as_float(g[2 * u + 1] & 0xFFFF0000u);
        }
    }

    ax = fmaxf(ax, 0.f); ay = fmaxf(ay, 0.f);
    h2b[(size_t)r * 64 + lane] = (unsigned)f2bf(ax) | ((unsigned)f2bf(ay) << 16);
}

// ---------------------------------------------------------------------------
// fc2 via bf16 MFMA 16x16x32 + bias + log_softmax, all in registers.
// ---------------------------------------------------------------------------
__global__ __launch_bounds__(256) void fc2_mfma(const unsigned short* __restrict__ h2b,
                                                const unsigned short* __restrict__ W2T,
                                                const float* __restrict__ b2,
                                                float* __restrict__ out, int N)
{
    const int t    = threadIdx.x;
    const int lane = t & 63;
    const int w    = t >> 6;
    const int quad = lane >> 4;
    const int ln15 = lane & 15;
    const int row0 = blockIdx.x * 64;

    int arow = row0 + w * 16 + ln15;
    if (arow >= N) arow = N - 1;

    f32x4 acc[4];
#pragma unroll
    for (int i = 0; i < 4; ++i) acc[i] = (f32x4){0.f, 0.f, 0.f, 0.f};

#pragma unroll
    for (int ks = 0; ks < 4; ++ks) {
        bf16x8 afrag = *(const bf16x8*)&h2b[(size_t)arow * HID + ks * 32 + quad * 8];
#pragma unroll
        for (int nt = 0; nt < 4; ++nt) {
            bf16x8 bfrag = *(const bf16x8*)&W2T[(size_t)(nt * 16 + ln15) * HID + ks * 32 + quad * 8];
            acc[nt] = __builtin_amdgcn_mfma_f32_16x16x32_bf16(afrag, bfrag, acc[nt], 0, 0, 0);
        }
    }

    float bias[4];
#pragma unroll
    for (int nt = 0; nt < 4; ++nt) bias[nt] = b2[nt * 16 + ln15];

#pragma unroll
    for (int r = 0; r < 4; ++r) {
        float v[4];
#pragma unroll
        for (int nt = 0; nt < 4; ++nt) v[nt] = acc[nt][r] + bias[nt];

        float m = fmaxf(fmaxf(v[0], v[1]), fmaxf(v[2], v[3]));
#pragma unroll
        for (int o = 1; o < 16; o <<= 1) m = fmaxf(m, __shfl_xor(m, o));
        float s = __expf(v[0] - m) + __expf(v[1] - m) +
                  __expf(v[2] - m) + __expf(v[3] - m);
#pragma unroll
        for (int o = 1; o < 16; o <<= 1) s += __shfl_xor(s, o);
        float ls = __logf(s);

        int grow = row0 + w * 16 + quad * 4 + r;
        if (grow < N) {
#pragma unroll
            for (int nt = 0; nt < 4; ++nt)
                out[(size_t)grow * OUT_DIM + nt * 16 + ln15] = v[nt] - m - ls;
        }
    }
}

extern "C" void kernel_launch(void* const* d_in, const int* in_sizes, int n_in,
                              void* d_out, int out_size, void* d_ws, size_t ws_size,
                              hipStream_t stream) {
    const float* feat = (const float*)d_in[0];
    const int*   erow = (const int*)d_in[1];
    const int*   ecol = (const int*)d_in[2];
    const float* eval = (const float*)d_in[3];
    const float* W1   = (const float*)d_in[4];
    const float* b1   = (const float*)d_in[5];
    const float* W2   = (const float*)d_in[6];
    const float* b2   = (const float*)d_in[7];
    float*       out  = (float*)d_out;

    const int N = in_sizes[0] / IN_DIM;
    const int E = in_sizes[1];

    // ws: h1b 25.6MB | h2b 25.6MB | binned 28.8MB | edges2 34.4MB |
    //     rowIdx 0.8MB | W1T 64KB | W2T 16KB | gCursor 50KB
    unsigned short* h1b    = (unsigned short*)d_ws;
    unsigned short* h2b    = h1b + (size_t)N * HID;
    int2*           binned = (int2*)(h2b + (size_t)N * HID);
    int2*           edges2 = binned + (size_t)NBUCK * CAP;
    int2*           rowIdx = edges2 + (size_t)NBUCK * CAP2;
    unsigned short* W1T    = (unsigned short*)(rowIdx + N);
    unsigned short* W2T    = W1T + IN_DIM * HID;
    int*            gCursor= (int*)(W2T + HID * OUT_DIM);

    hipMemsetAsync(gCursor, 0, NBUCK * GC_STRIDE * sizeof(int), stream);

    w1t_kernel<<<(IN_DIM * HID) / 256, 256, 0, stream>>>(W1, W1T);
    w2t_kernel<<<(HID * OUT_DIM) / 256, 256, 0, stream>>>(W2, W2T);
    fc1_mfma<<<(N + 63) / 64, 256, 0, stream>>>(feat, W1T, b1, h1b, N);
    bin_kernel<<<(E + CHUNK - 1) / CHUNK, 256, 0, stream>>>(erow, ecol, eval,
                                                            gCursor, binned, E);
    sort_bucket3<<<NBUCK, 256, 0, stream>>>(gCursor, binned, edges2, rowIdx, N);

    const int nblk = (N + 3) / 4;          // one wave per row
    spmm_kernel<<<nblk, 256, 0, stream>>>(rowIdx, edges2, h1b,
                                          (unsigned*)h2b, N);
    fc2_mfma<<<(N + 63) / 64, 256, 0, stream>>>(h2b, W2T, b2, out, N);
}

// Round 3
// 495.762 us; speedup vs baseline: 1.0447x; 1.0395x over previous
//
#include <hip/hip_runtime.h>
#include <math.h>

constexpr int IN_DIM  = 256;
constexpr int HID     = 128;
constexpr int OUT_DIM = 64;

constexpr int BROWS   = 128;                 // rows per bucket
constexpr int NBUCK   = 782;                 // ceil(100000/128)
constexpr int CAP     = 4608;                // mean 4096 + 8 sigma (binned)
constexpr int CAP2    = 5504;                // CAP + 128*7 (row-padded edges2), mult of 8
constexpr int CHUNK   = 8192;                // edges per bin block
constexpr int GC_STRIDE = 16;                // 64B line per cursor (atomic de-contention)

typedef short  bf16x8 __attribute__((ext_vector_type(8)));
typedef float  f32x4  __attribute__((ext_vector_type(4)));
typedef float  f32x2  __attribute__((ext_vector_type(2)));
typedef int    i32x4  __attribute__((ext_vector_type(4)));

__device__ __forceinline__ unsigned short f2bf(float x) {
    union { float f; unsigned u; } v; v.f = x;
    unsigned r = v.u + 0x7FFF + ((v.u >> 16) & 1);   // RNE
    return (unsigned short)(r >> 16);
}

// ---------------------------------------------------------------------------
// wt_kernel: fused bf16 transposes of W1 and W2 (one launch).
// W1T[n][k] n<128,k<256 ; W2T[n][k] n<64,k<128.
// ---------------------------------------------------------------------------
__global__ __launch_bounds__(256) void wt_kernel(const float* __restrict__ W1,
                                                 const float* __restrict__ W2,
                                                 unsigned short* __restrict__ W1T,
                                                 unsigned short* __restrict__ W2T)
{
    int idx = blockIdx.x * 256 + threadIdx.x;
    if (idx < IN_DIM * HID) {                    // 32768: W1, idx = k*128+n
        int k = idx >> 7;
        int n = idx & 127;
        W1T[n * IN_DIM + k] = f2bf(W1[idx]);
    } else {                                     // 8192: W2, j = k*64+n
        int j = idx - IN_DIM * HID;
        int k = j >> 6;
        int n = j & 63;
        W2T[n * HID + k] = f2bf(W2[j]);
    }
}

// ---------------------------------------------------------------------------
// fc1 via bf16 MFMA 16x16x32. Full K=256 staged once (33 KB LDS, 1 barrier).
// ---------------------------------------------------------------------------
constexpr int PADK = 264;   // 256 + 8 bf16 pad

__global__ __launch_bounds__(256) void fc1_mfma(const float* __restrict__ feat,
                                                const unsigned short* __restrict__ W1T,
                                                const float* __restrict__ b1,
                                                unsigned short* __restrict__ h1b, int N)
{
    __shared__ unsigned short sA[64 * PADK];
    const int t    = threadIdx.x;
    const int lane = t & 63;
    const int w    = t >> 6;
    const int quad = lane >> 4;
    const int ln15 = lane & 15;
    const int row0 = blockIdx.x * 64;

#pragma unroll
    for (int i = 0; i < 16; ++i) {
        int flat = i * 256 + t;          // 0..4095
        int r    = flat >> 6;
        int k4   = flat & 63;
        int gr   = row0 + r;
        float4 v = make_float4(0.f, 0.f, 0.f, 0.f);
        if (gr < N)
            v = *(const float4*)&feat[(size_t)gr * IN_DIM + k4 * 4];
        ushort4 o;
        o.x = f2bf(v.x); o.y = f2bf(v.y); o.z = f2bf(v.z); o.w = f2bf(v.w);
        *(ushort4*)&sA[r * PADK + k4 * 4] = o;
    }
    __syncthreads();

    f32x4 acc[8];
#pragma unroll
    for (int i = 0; i < 8; ++i) acc[i] = (f32x4){0.f, 0.f, 0.f, 0.f};

#pragma unroll
    for (int ks = 0; ks < 8; ++ks) {
        bf16x8 afrag = *(const bf16x8*)&sA[(w * 16 + ln15) * PADK + ks * 32 + quad * 8];
#pragma unroll
        for (int nt = 0; nt < 8; ++nt) {
            bf16x8 bfrag = *(const bf16x8*)&W1T[(size_t)(nt * 16 + ln15) * IN_DIM + ks * 32 + quad * 8];
            acc[nt] = __builtin_amdgcn_mfma_f32_16x16x32_bf16(afrag, bfrag, acc[nt], 0, 0, 0);
        }
    }

#pragma unroll
    for (int nt = 0; nt < 8; ++nt) {
        int col = nt * 16 + ln15;
        float bias = b1[col];
#pragma unroll
        for (int r = 0; r < 4; ++r) {
            int grow = row0 + w * 16 + quad * 4 + r;
            if (grow < N)
                h1b[(size_t)grow * HID + col] = f2bf(acc[nt][r] + bias);
        }
    }
}

// ---------------------------------------------------------------------------
// bin: bucket edges by row>>7. Entry x = (col<<8) | (row&127)<<25.
// 1024 threads/block (was 256): grid is fixed at E/CHUNK=391 blocks, so
// block size is the only occupancy lever -> 16 waves/block, up to 32/CU.
// Round-2 counters: 14% occupancy, VALU 1.5% -> pure latency starvation.
// ---------------------------------------------------------------------------
__global__ __launch_bounds__(1024) void bin_kernel(const int* __restrict__ erow,
                                                   const int* __restrict__ ecol,
                                                   const float* __restrict__ eval,
                                                   int* __restrict__ gCursor,
                                                   int2* __restrict__ binned, int E)
{
    __shared__ int sCnt[NBUCK];
    __shared__ int sBase[NBUCK];
    const int t = threadIdx.x;
    const int e0 = blockIdx.x * CHUNK;
    const int eEnd = min(e0 + CHUNK, E);

    for (int i = t; i < NBUCK; i += 1024) sCnt[i] = 0;
    __syncthreads();

    for (int e = e0 + t; e < eEnd; e += 1024)
        atomicAdd(&sCnt[erow[e] >> 7], 1);
    __syncthreads();

    for (int i = t; i < NBUCK; i += 1024) {
        int c = sCnt[i];
        sBase[i] = c ? atomicAdd(&gCursor[i * GC_STRIDE], c) : 0;
        sCnt[i] = 0;
    }
    __syncthreads();

    for (int e = e0 + t; e < eEnd; e += 1024) {
        int   r = erow[e];
        int   c = ecol[e];
        float v = eval[e];
        int   b = r >> 7;
        int off = sBase[b] + atomicAdd(&sCnt[b], 1);
        if (off < CAP)
            binned[(size_t)b * CAP + off] = make_int2((c << 8) | ((r & 127) << 25),
                                                      __float_as_int(v));
    }
}

// ---------------------------------------------------------------------------
// sort_bucket3: per-bucket row-grouping with per-row PADDING to a multiple
// of 8 edges (pad = col 0, val 0.0 -> gather of h1 row 0, times zero).
// ---------------------------------------------------------------------------
__global__ __launch_bounds__(256) void sort_bucket3(const int* __restrict__ gCursor,
                                                    const int2* __restrict__ binned,
                                                    int2* __restrict__ edges2,
                                                    int2* __restrict__ rowIdx, int N)
{
    __shared__ int sHist[BROWS];
    __shared__ int sStart[BROWS + 1];
    __shared__ int sCur[BROWS];
    const int t  = threadIdx.x;
    const int b  = blockIdx.x;
    const int nE = min(gCursor[b * GC_STRIDE], CAP);
    const size_t baseIn  = (size_t)b * CAP;
    const size_t baseOut = (size_t)b * CAP2;

    if (t < BROWS) sHist[t] = 0;
    __syncthreads();

    for (int i = t; i < nE; i += 256)
        atomicAdd(&sHist[(unsigned)binned[baseIn + i].x >> 25], 1);
    __syncthreads();

    if (t < BROWS) sStart[t + 1] = (sHist[t] + 7) & ~7;   // padded count
    if (t == 0) sStart[0] = 0;
    __syncthreads();
    for (int o = 1; o < BROWS; o <<= 1) {
        int v = 0;
        if (t < BROWS) {
            v = sStart[t + 1];
            if (t >= o) v += sStart[t + 1 - o];
        }
        __syncthreads();
        if (t < BROWS) sStart[t + 1] = v;
        __syncthreads();
    }
    if (t < BROWS) sCur[t] = sStart[t];
    __syncthreads();

    for (int i = t; i < nE; i += 256) {
        int2 p = binned[baseIn + i];
        int rl = (unsigned)p.x >> 25;
        int pos = atomicAdd(&sCur[rl], 1);
        edges2[baseOut + pos] = p;
    }

    // pad fill + rowIdx (pad slots [h, ph) are never touched by the scatter)
    if (t < BROWS) {
        int h  = sHist[t];
        int ph = (h + 7) & ~7;
        size_t p0 = baseOut + sStart[t];
        for (int k = h; k < ph; ++k)
            edges2[p0 + k] = make_int2(0, 0);
        int rr = b * BROWS + t;
        if (rr < N)
            rowIdx[rr] = make_int2((int)p0, (int)(p0 + ph));
    }
}

// ---------------------------------------------------------------------------
// spmm: gather-accumulate + relu, store bf16 h2. ONE wave per row.
// Row edge count is a multiple of 8 (padded), so only full pipelined batches.
// Accumulation in packed f32x2 (v_pk_fma_f32): one packed FMA per edge
// instead of two scalar FMAs (VALU was 37% busy in round 2).
// ---------------------------------------------------------------------------
__global__ __launch_bounds__(256) void spmm_kernel(const int2* __restrict__ rowIdx,
                                                   const int2* __restrict__ edges2,
                                                   const unsigned short* __restrict__ h1b,
                                                   unsigned* __restrict__ h2b, int N)
{
    const int lane  = threadIdx.x & 63;
    const int lane4 = lane * 4;
    const int r     = (blockIdx.x * blockDim.x + threadIdx.x) >> 6;
    if (r >= N) return;
    const char* h1base = (const char*)h1b;

    const int2 se = rowIdx[r];
    int j = se.x;
    const int jend = se.y;
    f32x2 acc = (f32x2){0.f, 0.f};

    for (; j + 16 <= jend; j += 16) {
        i32x4 q[8];
#pragma unroll
        for (int u = 0; u < 8; ++u)
            q[u] = __builtin_nontemporal_load((const i32x4*)&edges2[j + u * 2]);
        unsigned g[16];
#pragma unroll
        for (int u = 0; u < 8; ++u) {
            g[2 * u]     = *(const unsigned*)(h1base + (q[u].x & 0x01FFFFFF) + lane4);
            g[2 * u + 1] = *(const unsigned*)(h1base + (q[u].z & 0x01FFFFFF) + lane4);
        }
#pragma unroll
        for (int u = 0; u < 8; ++u) {
            f32x2 h0 = (f32x2){__uint_as_float(g[2 * u] << 16),
                               __uint_as_float(g[2 * u] & 0xFFFF0000u)};
            f32x2 h1 = (f32x2){__uint_as_float(g[2 * u + 1] << 16),
                               __uint_as_float(g[2 * u + 1] & 0xFFFF0000u)};
            acc += h0 * __int_as_float(q[u].y);
            acc += h1 * __int_as_float(q[u].w);
        }
    }
    if (j < jend) {   // exactly 8 remain (counts are multiples of 8)
        i32x4 q[4];
#pragma unroll
        for (int u = 0; u < 4; ++u)
            q[u] = __builtin_nontemporal_load((const i32x4*)&edges2[j + u * 2]);
        unsigned g[8];
#pragma unroll
        for (int u = 0; u < 4; ++u) {
            g[2 * u]     = *(const unsigned*)(h1base + (q[u].x & 0x01FFFFFF) + lane4);
            g[2 * u + 1] = *(const unsigned*)(h1base + (q[u].z & 0x01FFFFFF) + lane4);
        }
#pragma unroll
        for (int u = 0; u < 4; ++u) {
            f32x2 h0 = (f32x2){__uint_as_float(g[2 * u] << 16),
                               __uint_as_float(g[2 * u] & 0xFFFF0000u)};
            f32x2 h1 = (f32x2){__uint_as_float(g[2 * u + 1] << 16),
                               __uint_as_float(g[2 * u + 1] & 0xFFFF0000u)};
            acc += h0 * __int_as_float(q[u].y);
            acc += h1 * __int_as_float(q[u].w);
        }
    }

    float ax = fmaxf(acc.x, 0.f), ay = fmaxf(acc.y, 0.f);
    h2b[(size_t)r * 64 + lane] = (unsigned)f2bf(ax) | ((unsigned)f2bf(ay) << 16);
}

// ---------------------------------------------------------------------------
// fc2 via bf16 MFMA 16x16x32 + bias + log_softmax, all in registers.
// ---------------------------------------------------------------------------
__global__ __launch_bounds__(256) void fc2_mfma(const unsigned short* __restrict__ h2b,
                                                const unsigned short* __restrict__ W2T,
                                                const float* __restrict__ b2,
                                                float* __restrict__ out, int N)
{
    const int t    = threadIdx.x;
    const int lane = t & 63;
    const int w    = t >> 6;
    const int quad = lane >> 4;
    const int ln15 = lane & 15;
    const int row0 = blockIdx.x * 64;

    int arow = row0 + w * 16 + ln15;
    if (arow >= N) arow = N - 1;

    f32x4 acc[4];
#pragma unroll
    for (int i = 0; i < 4; ++i) acc[i] = (f32x4){0.f, 0.f, 0.f, 0.f};

#pragma unroll
    for (int ks = 0; ks < 4; ++ks) {
        bf16x8 afrag = *(const bf16x8*)&h2b[(size_t)arow * HID + ks * 32 + quad * 8];
#pragma unroll
        for (int nt = 0; nt < 4; ++nt) {
            bf16x8 bfrag = *(const bf16x8*)&W2T[(size_t)(nt * 16 + ln15) * HID + ks * 32 + quad * 8];
            acc[nt] = __builtin_amdgcn_mfma_f32_16x16x32_bf16(afrag, bfrag, acc[nt], 0, 0, 0);
        }
    }

    float bias[4];
#pragma unroll
    for (int nt = 0; nt < 4; ++nt) bias[nt] = b2[nt * 16 + ln15];

#pragma unroll
    for (int r = 0; r < 4; ++r) {
        float v[4];
#pragma unroll
        for (int nt = 0; nt < 4; ++nt) v[nt] = acc[nt][r] + bias[nt];

        float m = fmaxf(fmaxf(v[0], v[1]), fmaxf(v[2], v[3]));
#pragma unroll
        for (int o = 1; o < 16; o <<= 1) m = fmaxf(m, __shfl_xor(m, o));
        float s = __expf(v[0] - m) + __expf(v[1] - m) +
                  __expf(v[2] - m) + __expf(v[3] - m);
#pragma unroll
        for (int o = 1; o < 16; o <<= 1) s += __shfl_xor(s, o);
        float ls = __logf(s);

        int grow = row0 + w * 16 + quad * 4 + r;
        if (grow < N) {
#pragma unroll
            for (int nt = 0; nt < 4; ++nt)
                out[(size_t)grow * OUT_DIM + nt * 16 + ln15] = v[nt] - m - ls;
        }
    }
}

extern "C" void kernel_launch(void* const* d_in, const int* in_sizes, int n_in,
                              void* d_out, int out_size, void* d_ws, size_t ws_size,
                              hipStream_t stream) {
    const float* feat = (const float*)d_in[0];
    const int*   erow = (const int*)d_in[1];
    const int*   ecol = (const int*)d_in[2];
    const float* eval = (const float*)d_in[3];
    const float* W1   = (const float*)d_in[4];
    const float* b1   = (const float*)d_in[5];
    const float* W2   = (const float*)d_in[6];
    const float* b2   = (const float*)d_in[7];
    float*       out  = (float*)d_out;

    const int N = in_sizes[0] / IN_DIM;
    const int E = in_sizes[1];

    // ws: h1b 25.6MB | h2b 25.6MB | binned 28.8MB | edges2 34.4MB |
    //     rowIdx 0.8MB | W1T 64KB | W2T 16KB | gCursor 50KB
    unsigned short* h1b    = (unsigned short*)d_ws;
    unsigned short* h2b    = h1b + (size_t)N * HID;
    int2*           binned = (int2*)(h2b + (size_t)N * HID);
    int2*           edges2 = binned + (size_t)NBUCK * CAP;
    int2*           rowIdx = edges2 + (size_t)NBUCK * CAP2;
    unsigned short* W1T    = (unsigned short*)(rowIdx + N);
    unsigned short* W2T    = W1T + IN_DIM * HID;
    int*            gCursor= (int*)(W2T + HID * OUT_DIM);

    hipMemsetAsync(gCursor, 0, NBUCK * GC_STRIDE * sizeof(int), stream);

    wt_kernel<<<(IN_DIM * HID + HID * OUT_DIM) / 256, 256, 0, stream>>>(W1, W2, W1T, W2T);
    fc1_mfma<<<(N + 63) / 64, 256, 0, stream>>>(feat, W1T, b1, h1b, N);
    bin_kernel<<<(E + CHUNK - 1) / CHUNK, 1024, 0, stream>>>(erow, ecol, eval,
                                                             gCursor, binned, E);
    sort_bucket3<<<NBUCK, 256, 0, stream>>>(gCursor, binned, edges2, rowIdx, N);

    const int nblk = (N + 3) / 4;          // one wave per row
    spmm_kernel<<<nblk, 256, 0, stream>>>(rowIdx, edges2, h1b,
                                          (unsigned*)h2b, N);
    fc2_mfma<<<(N + 63) / 64, 256, 0, stream>>>(h2b, W2T, b2, out, N);
}

// Round 4
// 473.374 us; speedup vs baseline: 1.0941x; 1.0473x over previous
//
#include <hip/hip_runtime.h>
#include <math.h>

constexpr int IN_DIM  = 256;
constexpr int HID     = 128;
constexpr int OUT_DIM = 64;

constexpr int BROWS   = 128;                 // rows per bucket
constexpr int NBUCK   = 782;                 // ceil(100000/128)
constexpr int CAP     = 4608;                // mean 4096 + 8 sigma (binned)
constexpr int CAP2    = 5504;                // CAP + 128*7 (row-padded edges2), mult of 8
constexpr int CHUNK   = 8192;                // edges per bin block
constexpr int GC_STRIDE = 16;                // 64B line per cursor (atomic de-contention)

typedef short  bf16x8 __attribute__((ext_vector_type(8)));
typedef float  f32x4  __attribute__((ext_vector_type(4)));
typedef float  f32x2  __attribute__((ext_vector_type(2)));
typedef int    i32x4  __attribute__((ext_vector_type(4)));

__device__ __forceinline__ unsigned short f2bf(float x) {
    union { float f; unsigned u; } v; v.f = x;
    unsigned r = v.u + 0x7FFF + ((v.u >> 16) & 1);   // RNE
    return (unsigned short)(r >> 16);
}

// ---------------------------------------------------------------------------
// wt_kernel: fused bf16 transposes of W1 and W2 (one launch).
// W1T[n][k] n<128,k<256 ; W2T[n][k] n<64,k<128.
// ---------------------------------------------------------------------------
__global__ __launch_bounds__(256) void wt_kernel(const float* __restrict__ W1,
                                                 const float* __restrict__ W2,
                                                 unsigned short* __restrict__ W1T,
                                                 unsigned short* __restrict__ W2T)
{
    int idx = blockIdx.x * 256 + threadIdx.x;
    if (idx < IN_DIM * HID) {                    // 32768: W1, idx = k*128+n
        int k = idx >> 7;
        int n = idx & 127;
        W1T[n * IN_DIM + k] = f2bf(W1[idx]);
    } else {                                     // 8192: W2, j = k*64+n
        int j = idx - IN_DIM * HID;
        int k = j >> 6;
        int n = j & 63;
        W2T[n * HID + k] = f2bf(W2[j]);
    }
}

// ---------------------------------------------------------------------------
// fc1 via bf16 MFMA 16x16x32 — NO LDS staging (round-3 counters: 110 us,
// MfmaUtil 2.3%, VALU 5.7%, HBM 0.7 TB/s, occ 33% = latency-bound staging
// round-trip at 56 VGPRs). A-fragments read straight from global feat
// (fc2's pattern): row = row0+w*16+ln15, k = ks*32+quad*8, two float4 ->
// bf16x8. Each 64B feat line is hit by two loads of the same wave (quad
// pairs) -> L1 absorbs; no barrier, no LDS, full unroll lets the compiler
// hoist all A/B loads and overlap with MFMA.
// ---------------------------------------------------------------------------
__global__ __launch_bounds__(256) void fc1_mfma(const float* __restrict__ feat,
                                                const unsigned short* __restrict__ W1T,
                                                const float* __restrict__ b1,
                                                unsigned short* __restrict__ h1b, int N)
{
    const int t    = threadIdx.x;
    const int lane = t & 63;
    const int w    = t >> 6;
    const int quad = lane >> 4;
    const int ln15 = lane & 15;
    const int row0 = blockIdx.x * 64;

    int arow = row0 + w * 16 + ln15;           // clamp OOB (stores guarded)
    if (arow >= N) arow = N - 1;
    const float* aptr = feat + (size_t)arow * IN_DIM + quad * 8;

    f32x4 acc[8];
#pragma unroll
    for (int i = 0; i < 8; ++i) acc[i] = (f32x4){0.f, 0.f, 0.f, 0.f};

#pragma unroll
    for (int ks = 0; ks < 8; ++ks) {
        float4 a0 = *(const float4*)(aptr + ks * 32);
        float4 a1 = *(const float4*)(aptr + ks * 32 + 4);
        bf16x8 afrag;
        afrag[0] = (short)f2bf(a0.x); afrag[1] = (short)f2bf(a0.y);
        afrag[2] = (short)f2bf(a0.z); afrag[3] = (short)f2bf(a0.w);
        afrag[4] = (short)f2bf(a1.x); afrag[5] = (short)f2bf(a1.y);
        afrag[6] = (short)f2bf(a1.z); afrag[7] = (short)f2bf(a1.w);
#pragma unroll
        for (int nt = 0; nt < 8; ++nt) {
            bf16x8 bfrag = *(const bf16x8*)&W1T[(size_t)(nt * 16 + ln15) * IN_DIM + ks * 32 + quad * 8];
            acc[nt] = __builtin_amdgcn_mfma_f32_16x16x32_bf16(afrag, bfrag, acc[nt], 0, 0, 0);
        }
    }

#pragma unroll
    for (int nt = 0; nt < 8; ++nt) {
        int col = nt * 16 + ln15;
        float bias = b1[col];
#pragma unroll
        for (int r = 0; r < 4; ++r) {
            int grow = row0 + w * 16 + quad * 4 + r;
            if (grow < N)
                h1b[(size_t)grow * HID + col] = f2bf(acc[nt][r] + bias);
        }
    }
}

// ---------------------------------------------------------------------------
// bin: bucket edges by row>>7. Entry x = (col<<8) | (row&127)<<25.
// 1024 threads/block: grid fixed at E/CHUNK=391 blocks, block size is the
// occupancy lever (round-2: 14% occ, VALU 1.5% -> latency starved).
// ---------------------------------------------------------------------------
__global__ __launch_bounds__(1024) void bin_kernel(const int* __restrict__ erow,
                                                   const int* __restrict__ ecol,
                                                   const float* __restrict__ eval,
                                                   int* __restrict__ gCursor,
                                                   int2* __restrict__ binned, int E)
{
    __shared__ int sCnt[NBUCK];
    __shared__ int sBase[NBUCK];
    const int t = threadIdx.x;
    const int e0 = blockIdx.x * CHUNK;
    const int eEnd = min(e0 + CHUNK, E);

    for (int i = t; i < NBUCK; i += 1024) sCnt[i] = 0;
    __syncthreads();

    for (int e = e0 + t; e < eEnd; e += 1024)
        atomicAdd(&sCnt[erow[e] >> 7], 1);
    __syncthreads();

    for (int i = t; i < NBUCK; i += 1024) {
        int c = sCnt[i];
        sBase[i] = c ? atomicAdd(&gCursor[i * GC_STRIDE], c) : 0;
        sCnt[i] = 0;
    }
    __syncthreads();

    for (int e = e0 + t; e < eEnd; e += 1024) {
        int   r = erow[e];
        int   c = ecol[e];
        float v = eval[e];
        int   b = r >> 7;
        int off = sBase[b] + atomicAdd(&sCnt[b], 1);
        if (off < CAP)
            binned[(size_t)b * CAP + off] = make_int2((c << 8) | ((r & 127) << 25),
                                                      __float_as_int(v));
    }
}

// ---------------------------------------------------------------------------
// sort_bucket3: per-bucket row-grouping with per-row PADDING to a multiple
// of 8 edges (pad = col 0, val 0.0 -> gather of h1 row 0, times zero).
// ---------------------------------------------------------------------------
__global__ __launch_bounds__(256) void sort_bucket3(const int* __restrict__ gCursor,
                                                    const int2* __restrict__ binned,
                                                    int2* __restrict__ edges2,
                                                    int2* __restrict__ rowIdx, int N)
{
    __shared__ int sHist[BROWS];
    __shared__ int sStart[BROWS + 1];
    __shared__ int sCur[BROWS];
    const int t  = threadIdx.x;
    const int b  = blockIdx.x;
    const int nE = min(gCursor[b * GC_STRIDE], CAP);
    const size_t baseIn  = (size_t)b * CAP;
    const size_t baseOut = (size_t)b * CAP2;

    if (t < BROWS) sHist[t] = 0;
    __syncthreads();

    for (int i = t; i < nE; i += 256)
        atomicAdd(&sHist[(unsigned)binned[baseIn + i].x >> 25], 1);
    __syncthreads();

    if (t < BROWS) sStart[t + 1] = (sHist[t] + 7) & ~7;   // padded count
    if (t == 0) sStart[0] = 0;
    __syncthreads();
    for (int o = 1; o < BROWS; o <<= 1) {
        int v = 0;
        if (t < BROWS) {
            v = sStart[t + 1];
            if (t >= o) v += sStart[t + 1 - o];
        }
        __syncthreads();
        if (t < BROWS) sStart[t + 1] = v;
        __syncthreads();
    }
    if (t < BROWS) sCur[t] = sStart[t];
    __syncthreads();

    for (int i = t; i < nE; i += 256) {
        int2 p = binned[baseIn + i];
        int rl = (unsigned)p.x >> 25;
        int pos = atomicAdd(&sCur[rl], 1);
        edges2[baseOut + pos] = p;
    }

    // pad fill + rowIdx (pad slots [h, ph) are never touched by the scatter)
    if (t < BROWS) {
        int h  = sHist[t];
        int ph = (h + 7) & ~7;
        size_t p0 = baseOut + sStart[t];
        for (int k = h; k < ph; ++k)
            edges2[p0 + k] = make_int2(0, 0);
        int rr = b * BROWS + t;
        if (rr < N)
            rowIdx[rr] = make_int2((int)p0, (int)(p0 + ph));
    }
}

// ---------------------------------------------------------------------------
// spmm: gather-accumulate + relu, store bf16 h2. ONE wave per row.
// Row edge count is a multiple of 8 (padded), so only full pipelined batches.
// ---------------------------------------------------------------------------
__global__ __launch_bounds__(256) void spmm_kernel(const int2* __restrict__ rowIdx,
                                                   const int2* __restrict__ edges2,
                                                   const unsigned short* __restrict__ h1b,
                                                   unsigned* __restrict__ h2b, int N)
{
    const int lane  = threadIdx.x & 63;
    const int lane4 = lane * 4;
    const int r     = (blockIdx.x * blockDim.x + threadIdx.x) >> 6;
    if (r >= N) return;
    const char* h1base = (const char*)h1b;

    const int2 se = rowIdx[r];
    int j = se.x;
    const int jend = se.y;
    f32x2 acc = (f32x2){0.f, 0.f};

    for (; j + 16 <= jend; j += 16) {
        i32x4 q[8];
#pragma unroll
        for (int u = 0; u < 8; ++u)
            q[u] = __builtin_nontemporal_load((const i32x4*)&edges2[j + u * 2]);
        unsigned g[16];
#pragma unroll
        for (int u = 0; u < 8; ++u) {
            g[2 * u]     = *(const unsigned*)(h1base + (q[u].x & 0x01FFFFFF) + lane4);
            g[2 * u + 1] = *(const unsigned*)(h1base + (q[u].z & 0x01FFFFFF) + lane4);
        }
#pragma unroll
        for (int u = 0; u < 8; ++u) {
            f32x2 h0 = (f32x2){__uint_as_float(g[2 * u] << 16),
                               __uint_as_float(g[2 * u] & 0xFFFF0000u)};
            f32x2 h1 = (f32x2){__uint_as_float(g[2 * u + 1] << 16),
                               __uint_as_float(g[2 * u + 1] & 0xFFFF0000u)};
            acc += h0 * __int_as_float(q[u].y);
            acc += h1 * __int_as_float(q[u].w);
        }
    }
    if (j < jend) {   // exactly 8 remain (counts are multiples of 8)
        i32x4 q[4];
#pragma unroll
        for (int u = 0; u < 4; ++u)
            q[u] = __builtin_nontemporal_load((const i32x4*)&edges2[j + u * 2]);
        unsigned g[8];
#pragma unroll
        for (int u = 0; u < 4; ++u) {
            g[2 * u]     = *(const unsigned*)(h1base + (q[u].x & 0x01FFFFFF) + lane4);
            g[2 * u + 1] = *(const unsigned*)(h1base + (q[u].z & 0x01FFFFFF) + lane4);
        }
#pragma unroll
        for (int u = 0; u < 4; ++u) {
            f32x2 h0 = (f32x2){__uint_as_float(g[2 * u] << 16),
                               __uint_as_float(g[2 * u] & 0xFFFF0000u)};
            f32x2 h1 = (f32x2){__uint_as_float(g[2 * u + 1] << 16),
                               __uint_as_float(g[2 * u + 1] & 0xFFFF0000u)};
            acc += h0 * __int_as_float(q[u].y);
            acc += h1 * __int_as_float(q[u].w);
        }
    }

    float ax = fmaxf(acc.x, 0.f), ay = fmaxf(acc.y, 0.f);
    h2b[(size_t)r * 64 + lane] = (unsigned)f2bf(ax) | ((unsigned)f2bf(ay) << 16);
}

// ---------------------------------------------------------------------------
// fc2 via bf16 MFMA 16x16x32 + bias + log_softmax, all in registers.
// ---------------------------------------------------------------------------
__global__ __launch_bounds__(256) void fc2_mfma(const unsigned short* __restrict__ h2b,
                                                const unsigned short* __restrict__ W2T,
                                                const float* __restrict__ b2,
                                                float* __restrict__ out, int N)
{
    const int t    = threadIdx.x;
    const int lane = t & 63;
    const int w    = t >> 6;
    const int quad = lane >> 4;
    const int ln15 = lane & 15;
    const int row0 = blockIdx.x * 64;

    int arow = row0 + w * 16 + ln15;
    if (arow >= N) arow = N - 1;

    f32x4 acc[4];
#pragma unroll
    for (int i = 0; i < 4; ++i) acc[i] = (f32x4){0.f, 0.f, 0.f, 0.f};

#pragma unroll
    for (int ks = 0; ks < 4; ++ks) {
        bf16x8 afrag = *(const bf16x8*)&h2b[(size_t)arow * HID + ks * 32 + quad * 8];
#pragma unroll
        for (int nt = 0; nt < 4; ++nt) {
            bf16x8 bfrag = *(const bf16x8*)&W2T[(size_t)(nt * 16 + ln15) * HID + ks * 32 + quad * 8];
            acc[nt] = __builtin_amdgcn_mfma_f32_16x16x32_bf16(afrag, bfrag, acc[nt], 0, 0, 0);
        }
    }

    float bias[4];
#pragma unroll
    for (int nt = 0; nt < 4; ++nt) bias[nt] = b2[nt * 16 + ln15];

#pragma unroll
    for (int r = 0; r < 4; ++r) {
        float v[4];
#pragma unroll
        for (int nt = 0; nt < 4; ++nt) v[nt] = acc[nt][r] + bias[nt];

        float m = fmaxf(fmaxf(v[0], v[1]), fmaxf(v[2], v[3]));
#pragma unroll
        for (int o = 1; o < 16; o <<= 1) m = fmaxf(m, __shfl_xor(m, o));
        float s = __expf(v[0] - m) + __expf(v[1] - m) +
                  __expf(v[2] - m) + __expf(v[3] - m);
#pragma unroll
        for (int o = 1; o < 16; o <<= 1) s += __shfl_xor(s, o);
        float ls = __logf(s);

        int grow = row0 + w * 16 + quad * 4 + r;
        if (grow < N) {
#pragma unroll
            for (int nt = 0; nt < 4; ++nt)
                out[(size_t)grow * OUT_DIM + nt * 16 + ln15] = v[nt] - m - ls;
        }
    }
}

extern "C" void kernel_launch(void* const* d_in, const int* in_sizes, int n_in,
                              void* d_out, int out_size, void* d_ws, size_t ws_size,
                              hipStream_t stream) {
    const float* feat = (const float*)d_in[0];
    const int*   erow = (const int*)d_in[1];
    const int*   ecol = (const int*)d_in[2];
    const float* eval = (const float*)d_in[3];
    const float* W1   = (const float*)d_in[4];
    const float* b1   = (const float*)d_in[5];
    const float* W2   = (const float*)d_in[6];
    const float* b2   = (const float*)d_in[7];
    float*       out  = (float*)d_out;

    const int N = in_sizes[0] / IN_DIM;
    const int E = in_sizes[1];

    // ws: h1b 25.6MB | h2b 25.6MB | binned 28.8MB | edges2 34.4MB |
    //     rowIdx 0.8MB | W1T 64KB | W2T 16KB | gCursor 50KB
    unsigned short* h1b    = (unsigned short*)d_ws;
    unsigned short* h2b    = h1b + (size_t)N * HID;
    int2*           binned = (int2*)(h2b + (size_t)N * HID);
    int2*           edges2 = binned + (size_t)NBUCK * CAP;
    int2*           rowIdx = edges2 + (size_t)NBUCK * CAP2;
    unsigned short* W1T    = (unsigned short*)(rowIdx + N);
    unsigned short* W2T    = W1T + IN_DIM * HID;
    int*            gCursor= (int*)(W2T + HID * OUT_DIM);

    hipMemsetAsync(gCursor, 0, NBUCK * GC_STRIDE * sizeof(int), stream);

    wt_kernel<<<(IN_DIM * HID + HID * OUT_DIM) / 256, 256, 0, stream>>>(W1, W2, W1T, W2T);
    fc1_mfma<<<(N + 63) / 64, 256, 0, stream>>>(feat, W1T, b1, h1b, N);
    bin_kernel<<<(E + CHUNK - 1) / CHUNK, 1024, 0, stream>>>(erow, ecol, eval,
                                                             gCursor, binned, E);
    sort_bucket3<<<NBUCK, 256, 0, stream>>>(gCursor, binned, edges2, rowIdx, N);

    const int nblk = (N + 3) / 4;          // one wave per row
    spmm_kernel<<<nblk, 256, 0, stream>>>(rowIdx, edges2, h1b,
                                          (unsigned*)h2b, N);
    fc2_mfma<<<(N + 63) / 64, 256, 0, stream>>>(h2b, W2T, b2, out, N);
}

// Round 5
// 469.403 us; speedup vs baseline: 1.1033x; 1.0085x over previous
//
#include <hip/hip_runtime.h>
#include <math.h>

constexpr int IN_DIM  = 256;
constexpr int HID     = 128;
constexpr int OUT_DIM = 64;

constexpr int BROWS   = 128;                 // rows per bucket
constexpr int NBUCK   = 782;                 // ceil(100000/128)
constexpr int CAP     = 4608;                // mean 4096 + 8 sigma (binned)
constexpr int CAP2    = 5504;                // CAP + 128*7 (row-padded edges2), mult of 8
constexpr int CHUNK   = 8192;                // edges per bin block
constexpr int GC_STRIDE = 16;                // 64B line per cursor (atomic de-contention)

typedef short  bf16x8 __attribute__((ext_vector_type(8)));
typedef float  f32x4  __attribute__((ext_vector_type(4)));
typedef float  f32x2  __attribute__((ext_vector_type(2)));
typedef int    i32x4  __attribute__((ext_vector_type(4)));

__device__ __forceinline__ unsigned short f2bf(float x) {
    union { float f; unsigned u; } v; v.f = x;
    unsigned r = v.u + 0x7FFF + ((v.u >> 16) & 1);   // RNE
    return (unsigned short)(r >> 16);
}

// ---------------------------------------------------------------------------
// wt_kernel: fused bf16 transposes of W1 and W2 (one launch).
// W1T[n][k] n<128,k<256 ; W2T[n][k] n<64,k<128.
// ---------------------------------------------------------------------------
__global__ __launch_bounds__(256) void wt_kernel(const float* __restrict__ W1,
                                                 const float* __restrict__ W2,
                                                 unsigned short* __restrict__ W1T,
                                                 unsigned short* __restrict__ W2T)
{
    int idx = blockIdx.x * 256 + threadIdx.x;
    if (idx < IN_DIM * HID) {                    // 32768: W1, idx = k*128+n
        int k = idx >> 7;
        int n = idx & 127;
        W1T[n * IN_DIM + k] = f2bf(W1[idx]);
    } else {                                     // 8192: W2, j = k*64+n
        int j = idx - IN_DIM * HID;
        int k = j >> 6;
        int n = j & 63;
        W2T[n * HID + k] = f2bf(W2[j]);
    }
}

// ---------------------------------------------------------------------------
// fc1 via bf16 MFMA 16x16x32 — no LDS staging (round-3: staging round-trip
// was latency-bound at 110 us / MfmaUtil 2.3%). A-fragments straight from
// global feat (fc2's pattern).
// ---------------------------------------------------------------------------
__global__ __launch_bounds__(256) void fc1_mfma(const float* __restrict__ feat,
                                                const unsigned short* __restrict__ W1T,
                                                const float* __restrict__ b1,
                                                unsigned short* __restrict__ h1b, int N)
{
    const int t    = threadIdx.x;
    const int lane = t & 63;
    const int w    = t >> 6;
    const int quad = lane >> 4;
    const int ln15 = lane & 15;
    const int row0 = blockIdx.x * 64;

    int arow = row0 + w * 16 + ln15;           // clamp OOB (stores guarded)
    if (arow >= N) arow = N - 1;
    const float* aptr = feat + (size_t)arow * IN_DIM + quad * 8;

    f32x4 acc[8];
#pragma unroll
    for (int i = 0; i < 8; ++i) acc[i] = (f32x4){0.f, 0.f, 0.f, 0.f};

#pragma unroll
    for (int ks = 0; ks < 8; ++ks) {
        float4 a0 = *(const float4*)(aptr + ks * 32);
        float4 a1 = *(const float4*)(aptr + ks * 32 + 4);
        bf16x8 afrag;
        afrag[0] = (short)f2bf(a0.x); afrag[1] = (short)f2bf(a0.y);
        afrag[2] = (short)f2bf(a0.z); afrag[3] = (short)f2bf(a0.w);
        afrag[4] = (short)f2bf(a1.x); afrag[5] = (short)f2bf(a1.y);
        afrag[6] = (short)f2bf(a1.z); afrag[7] = (short)f2bf(a1.w);
#pragma unroll
        for (int nt = 0; nt < 8; ++nt) {
            bf16x8 bfrag = *(const bf16x8*)&W1T[(size_t)(nt * 16 + ln15) * IN_DIM + ks * 32 + quad * 8];
            acc[nt] = __builtin_amdgcn_mfma_f32_16x16x32_bf16(afrag, bfrag, acc[nt], 0, 0, 0);
        }
    }

#pragma unroll
    for (int nt = 0; nt < 8; ++nt) {
        int col = nt * 16 + ln15;
        float bias = b1[col];
#pragma unroll
        for (int r = 0; r < 4; ++r) {
            int grow = row0 + w * 16 + quad * 4 + r;
            if (grow < N)
                h1b[(size_t)grow * HID + col] = f2bf(acc[nt][r] + bias);
        }
    }
}

// ---------------------------------------------------------------------------
// bin: bucket edges by row>>7. Entry x = (col<<8) | (row&127)<<25.
// 1024 threads/block: grid fixed at E/CHUNK=391 blocks, block size is the
// occupancy lever (round-2: 14% occ, VALU 1.5% -> latency starved).
// ---------------------------------------------------------------------------
__global__ __launch_bounds__(1024) void bin_kernel(const int* __restrict__ erow,
                                                   const int* __restrict__ ecol,
                                                   const float* __restrict__ eval,
                                                   int* __restrict__ gCursor,
                                                   int2* __restrict__ binned, int E)
{
    __shared__ int sCnt[NBUCK];
    __shared__ int sBase[NBUCK];
    const int t = threadIdx.x;
    const int e0 = blockIdx.x * CHUNK;
    const int eEnd = min(e0 + CHUNK, E);

    for (int i = t; i < NBUCK; i += 1024) sCnt[i] = 0;
    __syncthreads();

    for (int e = e0 + t; e < eEnd; e += 1024)
        atomicAdd(&sCnt[erow[e] >> 7], 1);
    __syncthreads();

    for (int i = t; i < NBUCK; i += 1024) {
        int c = sCnt[i];
        sBase[i] = c ? atomicAdd(&gCursor[i * GC_STRIDE], c) : 0;
        sCnt[i] = 0;
    }
    __syncthreads();

    for (int e = e0 + t; e < eEnd; e += 1024) {
        int   r = erow[e];
        int   c = ecol[e];
        float v = eval[e];
        int   b = r >> 7;
        int off = sBase[b] + atomicAdd(&sCnt[b], 1);
        if (off < CAP)
            binned[(size_t)b * CAP + off] = make_int2((c << 8) | ((r & 127) << 25),
                                                      __float_as_int(v));
    }
}

// ---------------------------------------------------------------------------
// sort_bucket4: LDS-STAGED per-bucket row-grouping. binned is read from
// global exactly ONCE (was twice = 51 MB): the load pass stages edges into
// LDS sE[] (36 KB) while histogramming. After the scan, the scatter pass
// reads sE (LDS, sequential) and writes final slots in the 44 KB L2-resident
// edges2 window. Per-row counts padded to a multiple of 8 (pad = col 0,
// val 0 -> spmm gathers h1 row 0 times zero).
// LDS 37.6 KB -> 4 blocks/CU.
// ---------------------------------------------------------------------------
__global__ __launch_bounds__(256) void sort_bucket4(const int* __restrict__ gCursor,
                                                    const int2* __restrict__ binned,
                                                    int2* __restrict__ edges2,
                                                    int2* __restrict__ rowIdx, int N)
{
    __shared__ int2 sE[CAP];
    __shared__ int sHist[BROWS];
    __shared__ int sStart[BROWS + 1];
    __shared__ int sCur[BROWS];
    const int t  = threadIdx.x;
    const int b  = blockIdx.x;
    const int nE = min(gCursor[b * GC_STRIDE], CAP);
    const size_t baseIn  = (size_t)b * CAP;
    const size_t baseOut = (size_t)b * CAP2;

    if (t < BROWS) sHist[t] = 0;
    __syncthreads();

    // single global read: stage to LDS + histogram
    for (int i = t; i < nE; i += 256) {
        int2 p = binned[baseIn + i];
        sE[i] = p;
        atomicAdd(&sHist[(unsigned)p.x >> 25], 1);
    }
    __syncthreads();

    if (t < BROWS) sStart[t + 1] = (sHist[t] + 7) & ~7;   // padded count
    if (t == 0) sStart[0] = 0;
    __syncthreads();
    for (int o = 1; o < BROWS; o <<= 1) {
        int v = 0;
        if (t < BROWS) {
            v = sStart[t + 1];
            if (t >= o) v += sStart[t + 1 - o];
        }
        __syncthreads();
        if (t < BROWS) sStart[t + 1] = v;
        __syncthreads();
    }
    if (t < BROWS) sCur[t] = sStart[t];
    __syncthreads();

    // scatter from LDS (sequential reads) to final global slots
    for (int i = t; i < nE; i += 256) {
        int2 p = sE[i];
        int rl = (unsigned)p.x >> 25;
        int pos = atomicAdd(&sCur[rl], 1);
        edges2[baseOut + pos] = p;
    }

    // pad fill + rowIdx (pad slots [h, ph) are never touched by the scatter)
    if (t < BROWS) {
        int h  = sHist[t];
        int ph = (h + 7) & ~7;
        size_t p0 = baseOut + sStart[t];
        for (int k = h; k < ph; ++k)
            edges2[p0 + k] = make_int2(0, 0);
        int rr = b * BROWS + t;
        if (rr < N)
            rowIdx[rr] = make_int2((int)p0, (int)(p0 + ph));
    }
}

// ---------------------------------------------------------------------------
// spmm: gather-accumulate + relu, store bf16 h2. ONE wave per row.
// Row edge count is a multiple of 8 (padded), so only full pipelined batches.
// Bounded by the L2-miss/L3 gather path (~3.6 TB/s plateau across variants);
// left unchanged this round.
// ---------------------------------------------------------------------------
__global__ __launch_bounds__(256) void spmm_kernel(const int2* __restrict__ rowIdx,
                                                   const int2* __restrict__ edges2,
                                                   const unsigned short* __restrict__ h1b,
                                                   unsigned* __restrict__ h2b, int N)
{
    const int lane  = threadIdx.x & 63;
    const int lane4 = lane * 4;
    const int r     = (blockIdx.x * blockDim.x + threadIdx.x) >> 6;
    if (r >= N) return;
    const char* h1base = (const char*)h1b;

    const int2 se = rowIdx[r];
    int j = se.x;
    const int jend = se.y;
    f32x2 acc = (f32x2){0.f, 0.f};

    for (; j + 16 <= jend; j += 16) {
        i32x4 q[8];
#pragma unroll
        for (int u = 0; u < 8; ++u)
            q[u] = __builtin_nontemporal_load((const i32x4*)&edges2[j + u * 2]);
        unsigned g[16];
#pragma unroll
        for (int u = 0; u < 8; ++u) {
            g[2 * u]     = *(const unsigned*)(h1base + (q[u].x & 0x01FFFFFF) + lane4);
            g[2 * u + 1] = *(const unsigned*)(h1base + (q[u].z & 0x01FFFFFF) + lane4);
        }
#pragma unroll
        for (int u = 0; u < 8; ++u) {
            f32x2 h0 = (f32x2){__uint_as_float(g[2 * u] << 16),
                               __uint_as_float(g[2 * u] & 0xFFFF0000u)};
            f32x2 h1 = (f32x2){__uint_as_float(g[2 * u + 1] << 16),
                               __uint_as_float(g[2 * u + 1] & 0xFFFF0000u)};
            acc += h0 * __int_as_float(q[u].y);
            acc += h1 * __int_as_float(q[u].w);
        }
    }
    if (j < jend) {   // exactly 8 remain (counts are multiples of 8)
        i32x4 q[4];
#pragma unroll
        for (int u = 0; u < 4; ++u)
            q[u] = __builtin_nontemporal_load((const i32x4*)&edges2[j + u * 2]);
        unsigned g[8];
#pragma unroll
        for (int u = 0; u < 4; ++u) {
            g[2 * u]     = *(const unsigned*)(h1base + (q[u].x & 0x01FFFFFF) + lane4);
            g[2 * u + 1] = *(const unsigned*)(h1base + (q[u].z & 0x01FFFFFF) + lane4);
        }
#pragma unroll
        for (int u = 0; u < 4; ++u) {
            f32x2 h0 = (f32x2){__uint_as_float(g[2 * u] << 16),
                               __uint_as_float(g[2 * u] & 0xFFFF0000u)};
            f32x2 h1 = (f32x2){__uint_as_float(g[2 * u + 1] << 16),
                               __uint_as_float(g[2 * u + 1] & 0xFFFF0000u)};
            acc += h0 * __int_as_float(q[u].y);
            acc += h1 * __int_as_float(q[u].w);
        }
    }

    float ax = fmaxf(acc.x, 0.f), ay = fmaxf(acc.y, 0.f);
    h2b[(size_t)r * 64 + lane] = (unsigned)f2bf(ax) | ((unsigned)f2bf(ay) << 16);
}

// ---------------------------------------------------------------------------
// fc2 via bf16 MFMA 16x16x32 + bias + log_softmax, all in registers.
// ---------------------------------------------------------------------------
__global__ __launch_bounds__(256) void fc2_mfma(const unsigned short* __restrict__ h2b,
                                                const unsigned short* __restrict__ W2T,
                                                const float* __restrict__ b2,
                                                float* __restrict__ out, int N)
{
    const int t    = threadIdx.x;
    const int lane = t & 63;
    const int w    = t >> 6;
    const int quad = lane >> 4;
    const int ln15 = lane & 15;
    const int row0 = blockIdx.x * 64;

    int arow = row0 + w * 16 + ln15;
    if (arow >= N) arow = N - 1;

    f32x4 acc[4];
#pragma unroll
    for (int i = 0; i < 4; ++i) acc[i] = (f32x4){0.f, 0.f, 0.f, 0.f};

#pragma unroll
    for (int ks = 0; ks < 4; ++ks) {
        bf16x8 afrag = *(const bf16x8*)&h2b[(size_t)arow * HID + ks * 32 + quad * 8];
#pragma unroll
        for (int nt = 0; nt < 4; ++nt) {
            bf16x8 bfrag = *(const bf16x8*)&W2T[(size_t)(nt * 16 + ln15) * HID + ks * 32 + quad * 8];
            acc[nt] = __builtin_amdgcn_mfma_f32_16x16x32_bf16(afrag, bfrag, acc[nt], 0, 0, 0);
        }
    }

    float bias[4];
#pragma unroll
    for (int nt = 0; nt < 4; ++nt) bias[nt] = b2[nt * 16 + ln15];

#pragma unroll
    for (int r = 0; r < 4; ++r) {
        float v[4];
#pragma unroll
        for (int nt = 0; nt < 4; ++nt) v[nt] = acc[nt][r] + bias[nt];

        float m = fmaxf(fmaxf(v[0], v[1]), fmaxf(v[2], v[3]));
#pragma unroll
        for (int o = 1; o < 16; o <<= 1) m = fmaxf(m, __shfl_xor(m, o));
        float s = __expf(v[0] - m) + __expf(v[1] - m) +
                  __expf(v[2] - m) + __expf(v[3] - m);
#pragma unroll
        for (int o = 1; o < 16; o <<= 1) s += __shfl_xor(s, o);
        float ls = __logf(s);

        int grow = row0 + w * 16 + quad * 4 + r;
        if (grow < N) {
#pragma unroll
            for (int nt = 0; nt < 4; ++nt)
                out[(size_t)grow * OUT_DIM + nt * 16 + ln15] = v[nt] - m - ls;
        }
    }
}

extern "C" void kernel_launch(void* const* d_in, const int* in_sizes, int n_in,
                              void* d_out, int out_size, void* d_ws, size_t ws_size,
                              hipStream_t stream) {
    const float* feat = (const float*)d_in[0];
    const int*   erow = (const int*)d_in[1];
    const int*   ecol = (const int*)d_in[2];
    const float* eval = (const float*)d_in[3];
    const float* W1   = (const float*)d_in[4];
    const float* b1   = (const float*)d_in[5];
    const float* W2   = (const float*)d_in[6];
    const float* b2   = (const float*)d_in[7];
    float*       out  = (float*)d_out;

    const int N = in_sizes[0] / IN_DIM;
    const int E = in_sizes[1];

    // ws: h1b 25.6MB | h2b 25.6MB | binned 28.8MB | edges2 34.4MB |
    //     rowIdx 0.8MB | W1T 64KB | W2T 16KB | gCursor 50KB
    unsigned short* h1b    = (unsigned short*)d_ws;
    unsigned short* h2b    = h1b + (size_t)N * HID;
    int2*           binned = (int2*)(h2b + (size_t)N * HID);
    int2*           edges2 = binned + (size_t)NBUCK * CAP;
    int2*           rowIdx = edges2 + (size_t)NBUCK * CAP2;
    unsigned short* W1T    = (unsigned short*)(rowIdx + N);
    unsigned short* W2T    = W1T + IN_DIM * HID;
    int*            gCursor= (int*)(W2T + HID * OUT_DIM);

    hipMemsetAsync(gCursor, 0, NBUCK * GC_STRIDE * sizeof(int), stream);

    wt_kernel<<<(IN_DIM * HID + HID * OUT_DIM) / 256, 256, 0, stream>>>(W1, W2, W1T, W2T);
    fc1_mfma<<<(N + 63) / 64, 256, 0, stream>>>(feat, W1T, b1, h1b, N);
    bin_kernel<<<(E + CHUNK - 1) / CHUNK, 1024, 0, stream>>>(erow, ecol, eval,
                                                             gCursor, binned, E);
    sort_bucket4<<<NBUCK, 256, 0, stream>>>(gCursor, binned, edges2, rowIdx, N);

    const int nblk = (N + 3) / 4;          // one wave per row
    spmm_kernel<<<nblk, 256, 0, stream>>>(rowIdx, edges2, h1b,
                                          (unsigned*)h2b, N);
    fc2_mfma<<<(N + 63) / 64, 256, 0, stream>>>(h2b, W2T, b2, out, N);
}